// Round 7
// baseline (39.076 us; speedup 1.0000x reference)
//
#include <hip/hip_runtime.h>
#include <cfloat>

// Problem dims (fixed by reference)
#define BB   256   // batch
#define DIM  512
#define NN   196
#define BT   16    // b-tile in prep kernel
#define IT   32    // i-tile in prep kernel

// ---------------------------------------------------------------------------
// Kernel 1: prep — w[b,i] = (mem[b,i] + b_mem[i]) * v1[b,i] + v2[b,i]
// (byte-identical to round 6)
// ---------------------------------------------------------------------------
__global__ __launch_bounds__(1024, 1) void prep_kernel(
    const float* __restrict__ memory,    // (2,BB,DIM)
    const float* __restrict__ control,   // (2,BB,DIM)
    const float* __restrict__ W_mem,     // (DIM,DIM) row-major [k][i]
    const float* __restrict__ b_mem,     // (DIM)
    const float* __restrict__ W_concat,  // (2*DIM, DIM) row-major [c][j]
    const float* __restrict__ W_attn,    // (DIM,1)
    float* __restrict__ w_out)           // (BB, DIM)
{
    __shared__ float4 MU[8][DIM];    // 64 KB
    __shared__ float  buf[12288];    // 48 KB

    const int tid = threadIdx.x;
    const int il  = tid & 31;
    const int bg  = (tid >> 5) & 3;
    const int kg  = tid >> 7;
    const int b0  = blockIdx.x * BT;
    const int i0  = blockIdx.y * IT;

    const float* mem_in = memory  + (size_t)BB * DIM;
    const float* ctl_in = control + (size_t)BB * DIM;

    #pragma unroll
    for (int p4 = 0; p4 < 4; ++p4) {
        const int idx = p4 * 1024 + tid;
        const int k   = idx & 511;
        const int pp  = idx >> 9;
        const int bb  = b0 + pp * 2;
        const float wa = W_attn[k];
        MU[pp][k] = make_float4(
            mem_in[(size_t)bb       * DIM + k],
            ctl_in[(size_t)bb       * DIM + k] * wa,
            mem_in[(size_t)(bb + 1) * DIM + k],
            ctl_in[(size_t)(bb + 1) * DIM + k] * wa);
    }

    float am[4] = {0.f, 0.f, 0.f, 0.f};
    float a1[4] = {0.f, 0.f, 0.f, 0.f};
    float a2[4] = {0.f, 0.f, 0.f, 0.f};

    const int sr = tid >> 5;
    const int sc = tid & 15;
    const int h  = (tid >> 4) & 1;

    for (int kt = 0; kt < DIM; kt += 64) {
        __syncthreads();
        {
            const float4 q = *(const float4*)&W_concat[
                (size_t)(h * DIM + i0 + sr) * DIM + kt + sc * 4];
            const int kb = sc * 4;
            buf[((kb + 0) * 33 + sr) * 2 + h] = q.x;
            buf[((kb + 1) * 33 + sr) * 2 + h] = q.y;
            buf[((kb + 2) * 33 + sr) * 2 + h] = q.z;
            buf[((kb + 3) * 33 + sr) * 2 + h] = q.w;
        }
        __syncthreads();

        #pragma unroll
        for (int kk = 0; kk < 8; ++kk) {
            const int kl = kg * 8 + kk;
            const int k  = kt + kl;
            const float  wm  = W_mem[(size_t)k * DIM + i0 + il];
            const float2 c   = ((const float2*)buf)[kl * 33 + il];
            const float4 mu0 = MU[bg * 2 + 0][k];
            const float4 mu1 = MU[bg * 2 + 1][k];
            am[0] = fmaf(mu0.x, wm,  am[0]);
            a1[0] = fmaf(mu0.y, c.x, a1[0]);
            a2[0] = fmaf(mu0.y, c.y, a2[0]);
            am[1] = fmaf(mu0.z, wm,  am[1]);
            a1[1] = fmaf(mu0.w, c.x, a1[1]);
            a2[1] = fmaf(mu0.w, c.y, a2[1]);
            am[2] = fmaf(mu1.x, wm,  am[2]);
            a1[2] = fmaf(mu1.y, c.x, a1[2]);
            a2[2] = fmaf(mu1.y, c.y, a2[2]);
            am[3] = fmaf(mu1.z, wm,  am[3]);
            a1[3] = fmaf(mu1.w, c.x, a1[3]);
            a2[3] = fmaf(mu1.w, c.y, a2[3]);
        }
    }

    __syncthreads();
    #pragma unroll
    for (int j = 0; j < 4; ++j) {
        const int row = (kg * 16 + bg * 4 + j) * 32 + il;
        buf[row]        = am[j];
        buf[4096 + row] = a1[j];
        buf[8192 + row] = a2[j];
    }
    __syncthreads();
    if (tid < 512) {
        const int b = tid >> 5, ii = tid & 31;
        float sm = 0.f, s1 = 0.f, s2 = 0.f;
        #pragma unroll
        for (int t = 0; t < 8; ++t) {
            const int row = (t * 16 + b) * 32 + ii;
            sm += buf[row];
            s1 += buf[4096 + row];
            s2 += buf[8192 + row];
        }
        w_out[(size_t)(b0 + b) * DIM + i0 + ii] = (sm + b_mem[i0 + ii]) * s1 + s2;
    }
}

// ---------------------------------------------------------------------------
// Kernel 2a: read partials. grid (BB, 2): block (b, slab) streams d-rows
// [slab*256, slab*256+256) of know[b] (196 KB). 1024 thr, 2 blocks/CU ->
// 32 waves/CU (double round-6's latency tolerance). Wave ty owns 16 d-rows;
// lanes tx<49 own one float4 n-group. Writes part[b][slab][{lg,ks}][196].
// ---------------------------------------------------------------------------
__global__ __launch_bounds__(1024, 2) void read_part(
    const float* __restrict__ know,  // (BB, DIM, NN)
    const float* __restrict__ w,     // (BB, DIM)
    float* __restrict__ part)        // (BB, 2, 2, NN)
{
    __shared__ float  w_s[256];
    __shared__ float4 plg[16][50];
    __shared__ float4 pks[16][50];

    const int tx   = threadIdx.x;      // 0..63
    const int ty   = threadIdx.y;      // 0..15
    const int tid  = ty * 64 + tx;
    const int b    = blockIdx.x;
    const int slab = blockIdx.y;       // 0..1

    if (tid < 256) w_s[tid] = w[(size_t)b * DIM + slab * 256 + tid];
    __syncthreads();

    float4 lg = make_float4(0.f, 0.f, 0.f, 0.f);
    float4 ks = make_float4(0.f, 0.f, 0.f, 0.f);
    if (tx < 49) {
        const float4* kp = (const float4*)(know + (size_t)b * DIM * NN)
                         + (size_t)(slab * 256 + ty * 16) * 49 + tx;
        const float*  wp = w_s + ty * 16;
        #pragma unroll 8
        for (int dd = 0; dd < 16; ++dd) {
            const float4 kv = kp[(size_t)dd * 49];
            const float  wv = wp[dd];
            lg.x = fmaf(kv.x, wv, lg.x); lg.y = fmaf(kv.y, wv, lg.y);
            lg.z = fmaf(kv.z, wv, lg.z); lg.w = fmaf(kv.w, wv, lg.w);
            ks.x += kv.x; ks.y += kv.y; ks.z += kv.z; ks.w += kv.w;
        }
        plg[ty][tx] = lg;
        pks[ty][tx] = ks;
    }
    __syncthreads();

    if (tid < NN) {
        const int ng = tid >> 2, j = tid & 3;
        float lgn = 0.f, ksn = 0.f;
        #pragma unroll
        for (int t = 0; t < 16; ++t) {
            lgn += ((const float*)&plg[t][ng])[j];
            ksn += ((const float*)&pks[t][ng])[j];
        }
        float* pb = part + ((size_t)(b * 2 + slab) * 2) * NN;
        pb[tid]      = lgn;
        pb[NN + tid] = ksn;
    }
}

// ---------------------------------------------------------------------------
// Kernel 2b: combine 2 slabs + softmax + weighted write. grid BB x 256.
// ---------------------------------------------------------------------------
__global__ __launch_bounds__(256) void combine_kernel(
    const float* __restrict__ part,  // (BB, 2, 2, NN)
    float* __restrict__ out)         // (BB, NN)
{
    __shared__ float tmp[256];
    __shared__ float bc[2];

    const int tid = threadIdx.x;
    const int b   = blockIdx.x;
    const float* pb = part + (size_t)b * 4 * NN;

    float lg = 0.f, ks = 0.f;
    if (tid < NN) {
        lg = pb[tid] + pb[2 * NN + tid];
        ks = pb[NN + tid] + pb[3 * NN + tid];
    }

    tmp[tid] = (tid < NN) ? lg : -FLT_MAX;
    __syncthreads();
    if (tid < 64) {
        float m = fmaxf(fmaxf(tmp[tid], tmp[tid + 64]),
                        fmaxf(tmp[tid + 128], tmp[tid + 192]));
        #pragma unroll
        for (int o = 32; o; o >>= 1) m = fmaxf(m, __shfl_down(m, o));
        if (tid == 0) bc[0] = m;
    }
    __syncthreads();

    const float e = (tid < NN) ? __expf(lg - bc[0]) : 0.f;
    tmp[tid] = e;
    __syncthreads();
    if (tid < 64) {
        float s = tmp[tid] + tmp[tid + 64] + tmp[tid + 128] + tmp[tid + 192];
        #pragma unroll
        for (int o = 32; o; o >>= 1) s += __shfl_down(s, o);
        if (tid == 0) bc[1] = s;
    }
    __syncthreads();

    if (tid < NN) out[(size_t)b * NN + tid] = e / bc[1] * ks;
}

// ---------------------------------------------------------------------------
// Kernel 2 (fallback, r6-proven single-pass read) — used if ws too small.
// ---------------------------------------------------------------------------
__global__ __launch_bounds__(1024) void read_kernel(
    const float* __restrict__ know, const float* __restrict__ w,
    float* __restrict__ out)
{
    __shared__ float  w_s[DIM];
    __shared__ float4 part_lg[16][50];
    __shared__ float4 part_ks[16][50];
    __shared__ float  tmp[256];
    __shared__ float  bc[2];

    const int tx  = threadIdx.x;
    const int ty  = threadIdx.y;
    const int tid = ty * 64 + tx;
    const int b   = blockIdx.x;

    if (tid < DIM) w_s[tid] = w[(size_t)b * DIM + tid];
    __syncthreads();

    float4 lg = make_float4(0.f, 0.f, 0.f, 0.f);
    float4 ks = make_float4(0.f, 0.f, 0.f, 0.f);
    if (tx < 49) {
        const float4* kp = (const float4*)(know + (size_t)b * DIM * NN) + (size_t)(ty * 32) * 49 + tx;
        const float*  wp = w_s + ty * 32;
        #pragma unroll 8
        for (int dd = 0; dd < 32; ++dd) {
            const float4 kv = kp[(size_t)dd * 49];
            const float  wv = wp[dd];
            lg.x = fmaf(kv.x, wv, lg.x); lg.y = fmaf(kv.y, wv, lg.y);
            lg.z = fmaf(kv.z, wv, lg.z); lg.w = fmaf(kv.w, wv, lg.w);
            ks.x += kv.x; ks.y += kv.y; ks.z += kv.z; ks.w += kv.w;
        }
        part_lg[ty][tx] = lg;
        part_ks[ty][tx] = ks;
    }
    __syncthreads();

    float lgn = 0.f, ksn = 0.f;
    if (tid < NN) {
        const int ng = tid >> 2, j = tid & 3;
        #pragma unroll
        for (int t = 0; t < 16; ++t) {
            lgn += ((const float*)&part_lg[t][ng])[j];
            ksn += ((const float*)&part_ks[t][ng])[j];
        }
    }

    if (tid < 256) tmp[tid] = (tid < NN) ? lgn : -FLT_MAX;
    __syncthreads();
    if (tid < 64) {
        float m = fmaxf(fmaxf(tmp[tid], tmp[tid + 64]),
                        fmaxf(tmp[tid + 128], tmp[tid + 192]));
        #pragma unroll
        for (int o = 32; o; o >>= 1) m = fmaxf(m, __shfl_down(m, o));
        if (tid == 0) bc[0] = m;
    }
    __syncthreads();

    const float e = (tid < NN) ? __expf(lgn - bc[0]) : 0.f;
    if (tid < 256) tmp[tid] = e;
    __syncthreads();
    if (tid < 64) {
        float s = tmp[tid] + tmp[tid + 64] + tmp[tid + 128] + tmp[tid + 192];
        #pragma unroll
        for (int o = 32; o; o >>= 1) s += __shfl_down(s, o);
        if (tid == 0) bc[1] = s;
    }
    __syncthreads();

    if (tid < NN) out[(size_t)b * NN + tid] = e / bc[1] * ksn;
}

// ---------------------------------------------------------------------------
extern "C" void kernel_launch(void* const* d_in, const int* in_sizes, int n_in,
                              void* d_out, int out_size, void* d_ws, size_t ws_size,
                              hipStream_t stream) {
    const float* memory   = (const float*)d_in[0];
    const float* know     = (const float*)d_in[1];
    const float* control  = (const float*)d_in[2];
    const float* W_mem    = (const float*)d_in[3];
    const float* b_mem    = (const float*)d_in[4];
    const float* W_concat = (const float*)d_in[5];
    // d_in[6] = b_concat : uniform over n -> softmax-invariant, unused
    const float* W_attn   = (const float*)d_in[7];
    // d_in[8] = b_attn   : same, unused
    float* outp = (float*)d_out;

    const size_t W_BYTES    = (size_t)BB * DIM * sizeof(float);      // 512 KB
    const size_t PART_BYTES = (size_t)BB * 4 * NN * sizeof(float);   // 784 KB

    float* w_ws = (float*)d_ws;

    prep_kernel<<<dim3(BB / BT, DIM / IT), dim3(1024), 0, stream>>>(
        memory, control, W_mem, b_mem, W_concat, W_attn, w_ws);

    if (ws_size >= W_BYTES + PART_BYTES) {
        float* partp = (float*)((char*)d_ws + W_BYTES);
        read_part<<<dim3(BB, 2), dim3(64, 16), 0, stream>>>(know, w_ws, partp);
        combine_kernel<<<dim3(BB), dim3(256), 0, stream>>>(partp, outp);
    } else {
        read_kernel<<<dim3(BB), dim3(64, 16), 0, stream>>>(know, w_ws, outp);
    }
}